// Round 5
// baseline (916.626 us; speedup 1.0000x reference)
//
#include <hip/hip_runtime.h>

// ---------------------------------------------------------------------------
// Fused MHA block, bf16-MFMA pipeline (round 5 == round 4, resubmitted after
// GPU acquisition timeout; no code delta).
//   B=2, S=2048, D=1024, H=16, DK=64.
//   d_out = [x+proj_out : 4,194,304 f32][attn : 134,217,728 f32]
//   Deltas vs round 3: attn_k qt-balance remap; 8 waves/block (512 thr);
//                      1/8 score scale folded into Q projection epilogue.
// ---------------------------------------------------------------------------

typedef unsigned short u16;
typedef __attribute__((ext_vector_type(8))) short bf8_t;  // 8 bf16 (4 VGPR)
typedef __attribute__((ext_vector_type(4))) float f4_t;   // MFMA C/D

#define S_LEN 2048
#define NHEAD 16
#define RMS_EPS 1.1920929e-07f

__device__ inline u16 f2bf(float f) {  // round-to-nearest-even
  union { float f; unsigned int i; } v; v.f = f;
  unsigned int r = v.i + 0x7fffu + ((v.i >> 16) & 1u);
  return (u16)(r >> 16);
}

__device__ inline void gll16(const void* g, void* l) {
  __builtin_amdgcn_global_load_lds(
      (const __attribute__((address_space(1))) void*)g,
      (__attribute__((address_space(3))) void*)l, 16, 0, 0);
}

// ---------------- prep: weights fp32 -> bf16 (Wq|Wk|Wv concat, Wo), bias cat
__global__ __launch_bounds__(256) void prep_k(
    const float* __restrict__ wq, const float* __restrict__ wk,
    const float* __restrict__ wv, const float* __restrict__ wo,
    const float* __restrict__ bq, const float* __restrict__ bk,
    const float* __restrict__ bv, u16* __restrict__ Wcat,
    u16* __restrict__ Wob, float* __restrict__ bcat) {
  int idx = blockIdx.x * 256 + threadIdx.x;  // float4 granules
  if (idx < 786432) {  // Wcat: 3*1024*1024/4
    int z = idx / 262144, r = idx - z * 262144;
    const float* s = z == 0 ? wq : z == 1 ? wk : wv;
    float4 v = ((const float4*)s)[r];
    ((ushort4*)Wcat)[idx] =
        make_ushort4(f2bf(v.x), f2bf(v.y), f2bf(v.z), f2bf(v.w));
  } else if (idx < 786432 + 262144) {
    int r = idx - 786432;
    float4 v = ((const float4*)wo)[r];
    ((ushort4*)Wob)[r] = make_ushort4(f2bf(v.x), f2bf(v.y), f2bf(v.z), f2bf(v.w));
  } else if (idx < 786432 + 262144 + 768) {
    int r = idx - (786432 + 262144);
    int z = r >> 8, rr = r & 255;
    const float* s = z == 0 ? bq : z == 1 ? bk : bv;
    ((float4*)bcat)[r] = ((const float4*)s)[rr];
  }
}

// ---------------- RMSNorm -> bf16 ----------------
__global__ __launch_bounds__(256) void rmsnorm_k(const float* __restrict__ x,
                                                 const float* __restrict__ g,
                                                 u16* __restrict__ out) {
  int row = blockIdx.x, tid = threadIdx.x;
  float4 v = ((const float4*)(x + (size_t)row * 1024))[tid];
  float ss = v.x * v.x + v.y * v.y + v.z * v.z + v.w * v.w;
#pragma unroll
  for (int o = 32; o > 0; o >>= 1) ss += __shfl_xor(ss, o);
  __shared__ float red[4];
  int wid = tid >> 6, lane = tid & 63;
  if (lane == 0) red[wid] = ss;
  __syncthreads();
  float rs = rsqrtf((red[0] + red[1] + red[2] + red[3]) * (1.0f / 1024.0f) +
                    RMS_EPS);
  float4 gv = ((const float4*)g)[tid];
  ((ushort4*)(out + (size_t)row * 1024))[tid] =
      make_ushort4(f2bf(v.x * rs * gv.x), f2bf(v.y * rs * gv.y),
                   f2bf(v.z * rs * gv.z), f2bf(v.w * rs * gv.w));
}

// ---------------- bf16 MFMA GEMM, m97-style -------------------------------
// C[m][n] = sum_k A[m][k] * Bm[n][k]  (both row-major, K=1024), 128x128 tile,
// BK=64, 4 waves (2x2), acc 4x4 frags of 16x16x32. LDS linear; global_load_lds.
// MODE 0: + bcat[n]; Q (scaled by 1/8) / K -> [b,h,s,64] bf16, V -> [bh][d][s].
// MODE 1: + bias[n] + resid[m][n] -> fp32 out1[m][n].
template <int MODE>
__global__ __launch_bounds__(256, 2) void gemm_mfma(
    const u16* __restrict__ A, const u16* __restrict__ Bm,
    const float* __restrict__ bias, const float* __restrict__ resid,
    u16* __restrict__ Oq, u16* __restrict__ Ok, u16* __restrict__ Ov,
    float* __restrict__ out1) {
  __shared__ u16 As[128 * 64];
  __shared__ u16 Bs[128 * 64];
  const int m0 = blockIdx.y * 128, n0 = blockIdx.x * 128;
  const int tid = threadIdx.x, l = tid & 63, w = tid >> 6;
  const int wr = w >> 1, wc = w & 1, lg = l >> 4, lo = l & 15;
  const int arow = tid >> 3;           // staging row (0..31, +32/round)
  const int acol = (tid & 7) * 8;      // staging col in bf16

  f4_t acc[4][4];
#pragma unroll
  for (int i = 0; i < 4; i++)
#pragma unroll
    for (int j = 0; j < 4; j++) acc[i][j] = {0.f, 0.f, 0.f, 0.f};

  for (int k0 = 0; k0 < 1024; k0 += 64) {
#pragma unroll
    for (int r = 0; r < 4; r++) {
      gll16(A + (size_t)(m0 + r * 32 + arow) * 1024 + k0 + acol,
            (char*)As + r * 4096 + w * 1024);
      gll16(Bm + (size_t)(n0 + r * 32 + arow) * 1024 + k0 + acol,
            (char*)Bs + r * 4096 + w * 1024);
    }
    __syncthreads();
#pragma unroll
    for (int ks = 0; ks < 2; ks++) {
      bf8_t af[4], bf[4];
#pragma unroll
      for (int mi = 0; mi < 4; mi++)
        af[mi] = *(const bf8_t*)(As + (wr * 64 + mi * 16 + lo) * 64 + ks * 32 +
                                 lg * 8);
#pragma unroll
      for (int ni = 0; ni < 4; ni++)
        bf[ni] = *(const bf8_t*)(Bs + (wc * 64 + ni * 16 + lo) * 64 + ks * 32 +
                                 lg * 8);
#pragma unroll
      for (int mi = 0; mi < 4; mi++)
#pragma unroll
        for (int ni = 0; ni < 4; ni++)
          acc[mi][ni] = __builtin_amdgcn_mfma_f32_16x16x32_bf16(
              af[mi], bf[ni], acc[mi][ni], 0, 0, 0);
    }
    __syncthreads();
  }

  if (MODE == 0) {
    const int z = n0 >> 10;  // 128-wide block never crosses a 1024 boundary
    u16* ob = z == 0 ? Oq : z == 1 ? Ok : Ov;
    const float sc = (z == 0) ? 0.125f : 1.0f;  // fold score scale into Q
#pragma unroll
    for (int mi = 0; mi < 4; mi++)
#pragma unroll
      for (int ni = 0; ni < 4; ni++)
#pragma unroll
        for (int j = 0; j < 4; j++) {
          int m = m0 + wr * 64 + mi * 16 + lg * 4 + j;
          int n = n0 + wc * 64 + ni * 16 + lo;
          int nn = n & 1023, h = nn >> 6, d = nn & 63;
          int b = m >> 11, s = m & 2047;
          u16 vv = f2bf((acc[mi][ni][j] + bias[n]) * sc);
          if (z < 2)
            ob[(((size_t)(b * 16 + h) * 2048 + s) << 6) + d] = vv;
          else
            ob[((size_t)(b * 16 + h) * 64 + d) * 2048 + s] = vv;  // V^T
        }
  } else {
#pragma unroll
    for (int mi = 0; mi < 4; mi++)
#pragma unroll
      for (int ni = 0; ni < 4; ni++)
#pragma unroll
        for (int j = 0; j < 4; j++) {
          int m = m0 + wr * 64 + mi * 16 + lg * 4 + j;
          int n = n0 + wc * 64 + ni * 16 + lo;
          out1[(size_t)m * 1024 + n] =
              acc[mi][ni][j] + bias[n] + resid[(size_t)m * 1024 + n];
        }
  }
}

// ---------------- fused 2-pass flash attention (8 waves) --------------------
// Block: (xt, bh); qt = (bh<16)? xt : 15-xt  (balances co-resident pairs).
// Waves: wr = w>>2 (64 q-rows), wc = w&3 (32 k-cols quarter).
// Pass A: exact per-row (m,l) online; K-frags direct from global (L2-hot).
// Pass B: recompute S, P -> attn (fp32) + P-LDS (bf16); PV via Pl x Vs MFMA.
__global__ __launch_bounds__(512, 4) void attn_k(
    const u16* __restrict__ Qb, const u16* __restrict__ Kb,
    const u16* __restrict__ Vt, float* __restrict__ attn,
    u16* __restrict__ ctx) {
  const int bh = blockIdx.y;
  const int qt = (bh < 16) ? blockIdx.x : 15 - blockIdx.x;  // balance remap
  const int tid = threadIdx.x, l = tid & 63, w = tid >> 6;
  const int wr = w >> 2, wc = w & 3, lg = l >> 4, lo = l & 15;
  const int q0 = qt * 128, nkt = qt + 1;

  __shared__ u16 Pl[128 * 136];   // P tile bf16, pad 136
  __shared__ u16 Vs[64 * 136];    // V^T tile [d][k], pad 136
  __shared__ float mred[4][128], lred[4][128];

  const u16* Qp = Qb + (size_t)bh * (2048 * 64);
  const u16* Kp = Kb + (size_t)bh * (2048 * 64);
  const u16* Vp = Vt + (size_t)bh * (64 * 2048);
  float* Ap = attn + (size_t)bh * ((size_t)2048 * 2048);

  // zero-fill masked upper columns [nkt*128, 2048)
  {
    const int c0 = nkt * 128, cols4 = (2048 - c0) >> 2;
    float4 z4 = make_float4(0.f, 0.f, 0.f, 0.f);
    for (int r = 0; r < 128; r++) {
      float4* rp = (float4*)(Ap + (size_t)(q0 + r) * 2048 + c0);
      for (int c = tid; c < cols4; c += 512) rp[c] = z4;
    }
  }

  // Q fragments in registers (Q already carries the 1/8 scale)
  bf8_t qf[4][2];
#pragma unroll
  for (int mi = 0; mi < 4; mi++)
#pragma unroll
    for (int ks = 0; ks < 2; ks++)
      qf[mi][ks] = *(const bf8_t*)(Qp +
                                   (size_t)(q0 + wr * 64 + mi * 16 + lo) * 64 +
                                   ks * 32 + lg * 8);

  float rm[4][4], rl[4][4];
#pragma unroll
  for (int mi = 0; mi < 4; mi++)
#pragma unroll
    for (int j = 0; j < 4; j++) { rm[mi][j] = -3.0e38f; rl[mi][j] = 0.f; }

  // ---------------- pass A: exact row max & denom ----------------
  for (int kt = 0; kt < nkt; kt++) {
    const int k0 = kt * 128;
    f4_t sa[4][2];
#pragma unroll
    for (int i = 0; i < 4; i++)
#pragma unroll
      for (int j = 0; j < 2; j++) sa[i][j] = {0.f, 0.f, 0.f, 0.f};
#pragma unroll
    for (int ks = 0; ks < 2; ks++) {
      bf8_t kf[2];
#pragma unroll
      for (int ni = 0; ni < 2; ni++)
        kf[ni] = *(const bf8_t*)(Kp +
                                 (size_t)(k0 + wc * 32 + ni * 16 + lo) * 64 +
                                 ks * 32 + lg * 8);
#pragma unroll
      for (int mi = 0; mi < 4; mi++)
#pragma unroll
        for (int ni = 0; ni < 2; ni++)
          sa[mi][ni] = __builtin_amdgcn_mfma_f32_16x16x32_bf16(
              qf[mi][ks], kf[ni], sa[mi][ni], 0, 0, 0);
    }
    const bool diag = (kt == qt);
#pragma unroll
    for (int mi = 0; mi < 4; mi++) {
#pragma unroll
      for (int j = 0; j < 4; j++) {
        const int qrow = q0 + wr * 64 + mi * 16 + lg * 4 + j;
        float sv[2], tmax = -3.0e38f;
#pragma unroll
        for (int ni = 0; ni < 2; ni++) {
          float s = sa[mi][ni][j];
          if (diag && (k0 + wc * 32 + ni * 16 + lo > qrow)) s = -3.0e38f;
          sv[ni] = s;
          tmax = fmaxf(tmax, s);
        }
        tmax = fmaxf(tmax, __shfl_xor(tmax, 1));
        tmax = fmaxf(tmax, __shfl_xor(tmax, 2));
        tmax = fmaxf(tmax, __shfl_xor(tmax, 4));
        tmax = fmaxf(tmax, __shfl_xor(tmax, 8));
        const float nm = fmaxf(rm[mi][j], tmax);
        float ss = __expf(sv[0] - nm) + __expf(sv[1] - nm);
        ss += __shfl_xor(ss, 1);
        ss += __shfl_xor(ss, 2);
        ss += __shfl_xor(ss, 4);
        ss += __shfl_xor(ss, 8);
        rl[mi][j] = rl[mi][j] * __expf(rm[mi][j] - nm) + ss;
        rm[mi][j] = nm;
      }
    }
  }
  // combine the four k-quarters; bogus all-masked quarters vanish via exp
  if (lo == 0) {
#pragma unroll
    for (int mi = 0; mi < 4; mi++)
#pragma unroll
      for (int j = 0; j < 4; j++) {
        int r = wr * 64 + mi * 16 + lg * 4 + j;
        mred[wc][r] = rm[mi][j];
        lred[wc][r] = rl[mi][j];
      }
  }
  __syncthreads();
#pragma unroll
  for (int mi = 0; mi < 4; mi++)
#pragma unroll
    for (int j = 0; j < 4; j++) {
      int r = wr * 64 + mi * 16 + lg * 4 + j;
      float M = fmaxf(fmaxf(mred[0][r], mred[1][r]),
                      fmaxf(mred[2][r], mred[3][r]));
      float L = lred[0][r] * __expf(mred[0][r] - M) +
                lred[1][r] * __expf(mred[1][r] - M) +
                lred[2][r] * __expf(mred[2][r] - M) +
                lred[3][r] * __expf(mred[3][r] - M);
      rm[mi][j] = M;          // final row max
      rl[mi][j] = 1.0f / L;   // final 1/denominator
    }

  // ---------------- pass B: P write + PV ----------------
  f4_t oa[4];
#pragma unroll
  for (int i = 0; i < 4; i++) oa[i] = {0.f, 0.f, 0.f, 0.f};

  for (int kt = 0; kt < nkt; kt++) {
    const int k0 = kt * 128;
    f4_t sa[4][2];
#pragma unroll
    for (int i = 0; i < 4; i++)
#pragma unroll
      for (int j = 0; j < 2; j++) sa[i][j] = {0.f, 0.f, 0.f, 0.f};
#pragma unroll
    for (int ks = 0; ks < 2; ks++) {
      bf8_t kf[2];
#pragma unroll
      for (int ni = 0; ni < 2; ni++)
        kf[ni] = *(const bf8_t*)(Kp +
                                 (size_t)(k0 + wc * 32 + ni * 16 + lo) * 64 +
                                 ks * 32 + lg * 8);
#pragma unroll
      for (int mi = 0; mi < 4; mi++)
#pragma unroll
        for (int ni = 0; ni < 2; ni++)
          sa[mi][ni] = __builtin_amdgcn_mfma_f32_16x16x32_bf16(
              qf[mi][ks], kf[ni], sa[mi][ni], 0, 0, 0);
    }
    // stage V^T tile [64 d][128 k]
#pragma unroll
    for (int it = 0; it < 2; it++) {
      int gr = it * 512 + tid, d = gr >> 4, gcol = gr & 15;
      *(int4*)(&Vs[d * 136 + gcol * 8]) =
          *(const int4*)(Vp + (size_t)d * 2048 + k0 + gcol * 8);
    }
    const bool diag = (kt == qt);
#pragma unroll
    for (int mi = 0; mi < 4; mi++) {
#pragma unroll
      for (int j = 0; j < 4; j++) {
        const int qrow = q0 + wr * 64 + mi * 16 + lg * 4 + j;
        const int qloc = wr * 64 + mi * 16 + lg * 4 + j;
        float* arow = Ap + (size_t)qrow * 2048 + k0 + wc * 32;
#pragma unroll
        for (int ni = 0; ni < 2; ni++) {
          float p = __expf(sa[mi][ni][j] - rm[mi][j]) * rl[mi][j];
          if (diag && (k0 + wc * 32 + ni * 16 + lo > qrow)) p = 0.f;
          arow[ni * 16 + lo] = p;
          Pl[qloc * 136 + wc * 32 + ni * 16 + lo] = f2bf(p);
        }
      }
    }
    __syncthreads();
    // PV: wave (wr, wc): q 64 x d 16, contraction over k=128
#pragma unroll
    for (int ks = 0; ks < 4; ks++) {
      bf8_t pf[4], vf;
#pragma unroll
      for (int mi = 0; mi < 4; mi++)
        pf[mi] =
            *(const bf8_t*)(&Pl[(wr * 64 + mi * 16 + lo) * 136 + ks * 32 +
                                lg * 8]);
      vf = *(const bf8_t*)(&Vs[(wc * 16 + lo) * 136 + ks * 32 + lg * 8]);
#pragma unroll
      for (int mi = 0; mi < 4; mi++)
        oa[mi] = __builtin_amdgcn_mfma_f32_16x16x32_bf16(pf[mi], vf, oa[mi],
                                                         0, 0, 0);
    }
    __syncthreads();
  }

  // ctx bf16 [B*S][1024]
  const int b = bh >> 4, h = bh & 15;
#pragma unroll
  for (int mi = 0; mi < 4; mi++)
#pragma unroll
    for (int j = 0; j < 4; j++) {
      int q = q0 + wr * 64 + mi * 16 + lg * 4 + j;
      int d = wc * 16 + lo;
      ctx[(size_t)(b * 2048 + q) * 1024 + h * 64 + d] = f2bf(oa[mi][j]);
    }
}

// ---------------------------------------------------------------------------
extern "C" void kernel_launch(void* const* d_in, const int* in_sizes, int n_in,
                              void* d_out, int out_size, void* d_ws,
                              size_t ws_size, hipStream_t stream) {
  const float* x = (const float*)d_in[0];
  // d_in[1] = causal mask (statically known) -> unused
  const float* wq = (const float*)d_in[2];
  const float* bq = (const float*)d_in[3];
  const float* wk = (const float*)d_in[4];
  const float* bk = (const float*)d_in[5];
  const float* wv = (const float*)d_in[6];
  const float* bv = (const float*)d_in[7];
  const float* wo = (const float*)d_in[8];
  const float* bo = (const float*)d_in[9];
  const float* g = (const float*)d_in[10];

  float* out0 = (float*)d_out;
  float* attn = out0 + (size_t)4096 * 1024;

  u16* nrm = (u16*)d_ws;                    // [4096][1024] bf16
  u16* Wcat = nrm + (size_t)4096 * 1024;    // [3072][1024] bf16
  u16* Wob = Wcat + (size_t)3072 * 1024;    // [1024][1024] bf16
  u16* Qbb = Wob + (size_t)1024 * 1024;     // [2,16,2048,64] bf16 (pre-scaled)
  u16* Kbb = Qbb + (size_t)4194304;
  u16* Vtb = Kbb + (size_t)4194304;         // [32][64][2048] bf16 (V^T)
  u16* ctxb = Vtb + (size_t)4194304;        // [4096][1024] bf16
  float* bcat = (float*)(ctxb + (size_t)4194304);  // [3072] f32

  prep_k<<<4099, 256, 0, stream>>>(wq, wk, wv, wo, bq, bk, bv, Wcat, Wob, bcat);
  rmsnorm_k<<<4096, 256, 0, stream>>>(x, g, nrm);
  gemm_mfma<0><<<dim3(24, 32), 256, 0, stream>>>(nrm, Wcat, bcat, nullptr, Qbb,
                                                 Kbb, Vtb, nullptr);
  attn_k<<<dim3(16, 32), 512, 0, stream>>>(Qbb, Kbb, Vtb, attn, ctxb);
  gemm_mfma<1><<<dim3(8, 32), 256, 0, stream>>>(ctxb, Wob, bo, x, nullptr,
                                                nullptr, nullptr, out0);
}